// Round 2
// 158.055 us; speedup vs baseline: 1.0190x; 1.0190x over previous
//
#include <hip/hip_runtime.h>
#include <stdint.h>

// out[h,k,v] = 0.95*M[h,k,v] + sum_{b,s} rho[b,s]*K[b,s,h,k]*V[b,s,h,v]
// B=4, S=4096 (ROWS=16384), H=16, Dk=Dv=64.
//
// R8 = R7 with the tr-read address model corrected.
// R7 failed (absmax 475 ~= sqrt2*sigma*zmax -> wrong-column signature, not
// garbage): ds_read_b64_tr_b16 selects the COLUMN of the 128B [4][16]-bf16
// subtile via address bits [6:3] (elem j at (addr&~127) + 2*((addr>>3)&15)
// + 32*j; consistent with m156's layout formula under natural addr=base+8*l
// probing AND m162's uniform-addr observation). R7 encoded the column as
// +2*m (bits [4:1]) -> lanes read column m>>2. Fix: +8*m, and __align__(128)
// on the LDS tiles so the 128B-region arithmetic is exact.
//
// Structure (unchanged from R7):
//   - stage 32 s-rows/round of K (rho-scaled, bf16) + V into LDS, coalesced
//     float4 global loads (wave-op = 4 fully-dense 256B rows), subtiled
//     [s/4][c/16][4][16] bf16 layout, double-buffered, 1 barrier/round,
//     next round's globals issued before compute.
//   - waves own disjoint 32x32 OUTPUT quadrants (acc = 16 VGPR/lane), A/B
//     fragments via ds_read_b64_tr_b16, no LDS reduce, coalesced atomics.
//   - rule-18: lgkmcnt(0) + sched_barrier(0) between asm tr-reads and MFMA.
// Numerics identical to R6 (passed, absmax 2.0): bf16 round of (rho*k) and
// v, fp32 MFMA accumulation.

typedef __bf16  bf16x8  __attribute__((ext_vector_type(8)));
typedef __bf16  bf16x4  __attribute__((ext_vector_type(4)));
typedef short   s16x4   __attribute__((ext_vector_type(4)));
typedef float   floatx4 __attribute__((ext_vector_type(4)));

constexpr int HH   = 16;
constexpr int DK   = 64;
constexpr int DV   = 64;
constexpr int ROWS = 16384;
constexpr int NSLICE = 64;
constexpr int RPB  = ROWS / NSLICE;   // 256 rows per block
constexpr int TR   = 32;              // s-rows staged per round
constexpr int NR   = RPB / TR;        // 8 rounds
constexpr float DECAY = 0.95f;

__global__ __launch_bounds__(256) void init_out(const float* __restrict__ mem,
                                                float* __restrict__ out) {
    int i = blockIdx.x * 256 + threadIdx.x;
    out[i] = DECAY * mem[i];
}

__device__ __forceinline__ unsigned lds_off(const void* p) {
    // generic->LDS addrspace cast; value of an AS(3) pointer is the DS byte offset
    return (unsigned)(uintptr_t)(__attribute__((address_space(3))) const void*)p;
}

__global__ __launch_bounds__(256, 4) void accum(const float* __restrict__ keys,
                                                const float* __restrict__ values,
                                                const float* __restrict__ rho,
                                                float* __restrict__ out) {
    __shared__ __align__(128) __bf16 kb[2][TR * DK];   // 8 KiB
    __shared__ __align__(128) __bf16 vb[2][TR * DV];   // 8 KiB
    __shared__ float rs[RPB];                          // 1 KiB

    const int t    = threadIdx.x;
    const int lane = t & 63;
    const int w    = t >> 6;
    const int wr   = w >> 1;          // output-row quadrant (Dk)
    const int wc   = w & 1;           // output-col quadrant (Dv)
    const int m    = lane & 15;
    const int q    = lane >> 4;
    const int h    = blockIdx.y;
    const int row0 = blockIdx.x * RPB;

    rs[t] = rho[row0 + t];            // whole block's rho, once

    // staging geometry: thread covers float4 f = t and f = t+256 of the
    // 512-float4 (32 rows x 64 cols) round tile; 16 lanes span one 256B row.
    const int sl0 = t >> 4;           // 0..15  (+16 for second half)
    const int c0  = (t & 15) * 4;

    float4 pk[2], pv[2];

    auto loadr = [&](int r) {
        #pragma unroll
        for (int i = 0; i < 2; ++i) {
            const int sl = sl0 + i * 16;
            const size_t off = ((size_t)(row0 + r * TR + sl) * HH + h) * DK + c0;
            pk[i] = *(const float4*)(keys + off);
            pv[i] = *(const float4*)(values + off);
        }
    };
    auto writer = [&](int r, int b) {
        #pragma unroll
        for (int i = 0; i < 2; ++i) {
            const int sl = sl0 + i * 16;
            const float rv = rs[r * TR + sl];
            bf16x4 kh = {(__bf16)(pk[i].x * rv), (__bf16)(pk[i].y * rv),
                         (__bf16)(pk[i].z * rv), (__bf16)(pk[i].w * rv)};
            bf16x4 vh = {(__bf16)pv[i].x, (__bf16)pv[i].y,
                         (__bf16)pv[i].z, (__bf16)pv[i].w};
            // subtiled layout: elem(sl,c) at ((sl>>2)*4 + c>>4)*64 + (sl&3)*16 + (c&15)
            const int eo = ((sl >> 2) * 4 + (c0 >> 4)) * 64 + (sl & 3) * 16 + (c0 & 15);
            *(bf16x4*)&kb[b][eo] = kh;
            *(bf16x4*)&vb[b][eo] = vh;
        }
    };

    floatx4 acc[2][2];
    #pragma unroll
    for (int i = 0; i < 2; ++i)
        #pragma unroll
        for (int j = 0; j < 2; ++j)
            acc[i][j] = (floatx4){0.f, 0.f, 0.f, 0.f};

    loadr(0);
    __syncthreads();                  // rs visible
    writer(0, 0);

    for (int r = 0; r < NR; ++r) {
        const int cur = r & 1;
        if (r + 1 < NR) loadr(r + 1);     // issue next tile's globals early
        __syncthreads();                  // buf[cur] staged; buf[cur^1] free

        // A-frag elem j = Kscaled[q*8+j][wr*32 + mt*16 + m]  (layout per R6, verified)
        // tr-read: subtile base (128B-aligned) + 8*m; addr bits [6:3] = column m.
        // j=0..3 from subtile rb=2q; j=4..7 from rb=2q+1 at +512B.
        const unsigned abase = lds_off(&kb[cur][0]) + q * 1024 + 8 * m;
        const unsigned bbase = lds_off(&vb[cur][0]) + q * 1024 + 8 * m;

        s16x4 alo[2], ahi[2], blo[2], bhi[2];
        #pragma unroll
        for (int mt = 0; mt < 2; ++mt) {
            const unsigned ad = abase + (unsigned)((wr * 2 + mt) * 128);
            asm volatile("ds_read_b64_tr_b16 %0, %1" : "=v"(alo[mt]) : "v"(ad));
            asm volatile("ds_read_b64_tr_b16 %0, %1 offset:512" : "=v"(ahi[mt]) : "v"(ad));
        }
        #pragma unroll
        for (int nt = 0; nt < 2; ++nt) {
            const unsigned bd = bbase + (unsigned)((wc * 2 + nt) * 128);
            asm volatile("ds_read_b64_tr_b16 %0, %1" : "=v"(blo[nt]) : "v"(bd));
            asm volatile("ds_read_b64_tr_b16 %0, %1 offset:512" : "=v"(bhi[nt]) : "v"(bd));
        }
        asm volatile("s_waitcnt lgkmcnt(0)" ::: "memory");
        __builtin_amdgcn_sched_barrier(0);   // rule 18: pin consumers after the wait

        bf16x8 af[2], bfv[2];
        #pragma unroll
        for (int mt = 0; mt < 2; ++mt) {
            union { s16x4 hh[2]; bf16x8 v; } u;
            u.hh[0] = alo[mt]; u.hh[1] = ahi[mt];
            af[mt] = u.v;
        }
        #pragma unroll
        for (int nt = 0; nt < 2; ++nt) {
            union { s16x4 hh[2]; bf16x8 v; } u;
            u.hh[0] = blo[nt]; u.hh[1] = bhi[nt];
            bfv[nt] = u.v;
        }

        #pragma unroll
        for (int mt = 0; mt < 2; ++mt)
            #pragma unroll
            for (int nt = 0; nt < 2; ++nt)
                acc[mt][nt] = __builtin_amdgcn_mfma_f32_16x16x32_bf16(
                    af[mt], bfv[nt], acc[mt][nt], 0, 0, 0);

        if (r + 1 < NR) writer(r + 1, cur ^ 1);  // convert+stage into other buffer
    }

    // epilogue: each wave owns its 32x32 quadrant -> straight coalesced atomics.
    // C/D: [row = mt*16 + q*4 + g][col = nt*16 + m]  (verified mapping, R6)
    float* o = out + h * (DK * DV) + (wr * 32) * DV + wc * 32;
    #pragma unroll
    for (int mt = 0; mt < 2; ++mt)
        #pragma unroll
        for (int nt = 0; nt < 2; ++nt)
            #pragma unroll
            for (int g = 0; g < 4; ++g)
                atomicAdd(o + (mt * 16 + q * 4 + g) * DV + nt * 16 + m,
                          acc[mt][nt][g]);
}

extern "C" void kernel_launch(void* const* d_in, const int* in_sizes, int n_in,
                              void* d_out, int out_size, void* d_ws, size_t ws_size,
                              hipStream_t stream) {
    const float* mem    = (const float*)d_in[0];  // (H, Dk, Dv)
    const float* keys   = (const float*)d_in[1];  // (B, S, H, Dk)
    const float* values = (const float*)d_in[2];  // (B, S, H, Dv)
    const float* rho    = (const float*)d_in[3];  // (B, S)
    float* out = (float*)d_out;                   // (H, Dk, Dv)

    init_out<<<dim3((HH * DK * DV) / 256), dim3(256), 0, stream>>>(mem, out);

    dim3 grid(NSLICE, HH);
    accum<<<grid, dim3(256), 0, stream>>>(keys, values, rho, out);
}